// Round 5
// baseline (126.478 us; speedup 1.0000x reference)
//
#include <hip/hip_runtime.h>
#include <hip/hip_bf16.h>
#include <stdint.h>

typedef __attribute__((ext_vector_type(8))) short bf8_t;    // 8 bf16 in 4 VGPRs
typedef __attribute__((ext_vector_type(4))) short s4_t;
typedef __attribute__((ext_vector_type(4))) float f4_t;
typedef __attribute__((ext_vector_type(16))) float f16x_t;  // 32x32 mfma acc
typedef unsigned short u16;

#define GLOAD16(g, l) __builtin_amdgcn_global_load_lds(                                  \
    (const __attribute__((address_space(1))) void*)(g),                                  \
    (__attribute__((address_space(3))) void*)(l), 16, 0, 0)

__device__ __forceinline__ u16 f2bf(float f) {
    union { float f; unsigned u; } c; c.f = f;
    unsigned u = c.u;
    return (u16)((u + 0x7fffu + ((u >> 16) & 1u)) >> 16);   // RNE, inputs finite
}

__device__ __forceinline__ unsigned cvt_pk_bf16(float lo, float hi_) {
    unsigned r;
    asm("v_cvt_pk_bf16_f32 %0, %1, %2" : "=v"(r) : "v"(lo), "v"(hi_));
    return r;                                                // lo -> bits[15:0]
}

// ---------------- weights -> bf16 ----------------
__global__ void prep_kernel(const float* __restrict__ wq, const float* __restrict__ wk,
                            const float* __restrict__ wv, const float* __restrict__ wp,
                            const float* __restrict__ bq, const float* __restrict__ bk,
                            const float* __restrict__ bv,
                            u16* __restrict__ wcat, u16* __restrict__ wpb,
                            float* __restrict__ biasc) {
    int idx = blockIdx.x * 256 + threadIdx.x;
    if (idx < 196608) {                 // wcat [768][256]
        int o = idx >> 8, c = idx & 255;
        float v = (o < 256) ? wq[o * 256 + c]
                : (o < 512) ? wk[(o - 256) * 256 + c]
                            : wv[(o - 512) * 256 + c];
        wcat[idx] = f2bf(v);
    } else if (idx < 262144) {          // wp [256][256]
        wpb[idx - 196608] = f2bf(wp[idx - 196608]);
    } else if (idx < 262912) {          // bias concat [768]
        int i = idx - 262144;
        biasc[i] = (i < 256) ? bq[i] : (i < 512) ? bk[i - 256] : bv[i - 512];
    }
}

// ---------------- LayerNorm over C, single-pass ----------------
__global__ __launch_bounds__(512) void ln_kernel(const float* __restrict__ x,
                                                 const float* __restrict__ lw,
                                                 const float* __restrict__ lb,
                                                 u16* __restrict__ hn) {
    int tid = threadIdx.x;
    int tl = tid & 63, cg = tid >> 6;
    int tok = blockIdx.x * 64 + tl;
    int b = tok >> 10, n = tok & 1023;
    const float* xb = x + (size_t)b * 262144 + n;     // stride 1024 over c
    int ch0 = cg * 32;
    float v[32];
    float s = 0.f, s2 = 0.f;
    #pragma unroll
    for (int j = 0; j < 32; j++) {
        v[j] = xb[(size_t)(ch0 + j) * 1024];
        s += v[j]; s2 += v[j] * v[j];
    }
    __shared__ float2 red[8][64];
    red[cg][tl] = make_float2(s, s2);
    __syncthreads();
    s = 0.f; s2 = 0.f;
    #pragma unroll
    for (int g = 0; g < 8; g++) { float2 p = red[g][tl]; s += p.x; s2 += p.y; }
    float mean = s * 0.00390625f;
    float var  = s2 * 0.00390625f - mean * mean;
    float rstd = rsqrtf(var + 1e-6f);
    u16* hr = hn + (size_t)tok * 256 + ch0;
    #pragma unroll
    for (int j8 = 0; j8 < 4; j8++) {
        bf8_t pk;
        #pragma unroll
        for (int j = 0; j < 8; j++) {
            int c = j8 * 8 + j;
            float y = (v[c] - mean) * rstd * lw[ch0 + c] + lb[ch0 + c];
            pk[j] = (short)f2bf(y);
        }
        *(bf8_t*)&hr[j8 * 8] = pk;
    }
}

// ---------------- generic B^T bf16 GEMM, 128x128 tile, m97 structure ----------------
// EPI: 0 = QKV (+bias, Q scaled by 1/16, bf16 out)   3 = PROJ (+bias + residual, f32 out)
template <int EPI>
__global__ __launch_bounds__(256, 2) void gemm_bt(
    const u16* __restrict__ A, const u16* __restrict__ B, void* __restrict__ Cp,
    int lda, int ldb, int ldc, int nk,
    long sA, long sB, long sC,
    const float* __restrict__ aux1, const float* __restrict__ aux2) {
    __shared__ u16 lsA[128 * 32];
    __shared__ u16 lsB[128 * 32];
    const int tid = threadIdx.x;
    const int z = blockIdx.z;
    const int m0 = blockIdx.x * 128, n0 = blockIdx.y * 128;
    const int lane = tid & 63;
    const int w = tid >> 6, wm = w >> 1, wn = w & 1;
    const int lm = lane & 15, lg = lane >> 4;
    const int sr = tid >> 2, sc = (tid & 3) * 8;

    const u16* ga = A + (size_t)z * sA + (size_t)(m0 + sr) * lda + sc;
    const u16* gb = B + (size_t)z * sB + (size_t)(n0 + sr) * ldb + sc;
    u16* la  = &lsA[sr * 32 + sc];
    u16* lb2 = &lsB[sr * 32 + sc];

    f4_t acc[4][4];
    #pragma unroll
    for (int i = 0; i < 4; i++)
        #pragma unroll
        for (int j = 0; j < 4; j++) acc[i][j] = (f4_t)0.0f;

    for (int kt = 0; kt < nk; ++kt) {
        GLOAD16(ga, la);
        GLOAD16(ga + (size_t)64 * lda, la + 64 * 32);
        GLOAD16(gb, lb2);
        GLOAD16(gb + (size_t)64 * ldb, lb2 + 64 * 32);
        ga += 32; gb += 32;
        __syncthreads();
        bf8_t af[4], bfv[4];
        #pragma unroll
        for (int i = 0; i < 4; i++)
            af[i] = *(const bf8_t*)&lsA[(wm * 64 + i * 16 + lm) * 32 + lg * 8];
        #pragma unroll
        for (int i = 0; i < 4; i++)
            bfv[i] = *(const bf8_t*)&lsB[(wn * 64 + i * 16 + lm) * 32 + lg * 8];
        #pragma unroll
        for (int i = 0; i < 4; i++)
            #pragma unroll
            for (int j = 0; j < 4; j++)
                acc[i][j] = __builtin_amdgcn_mfma_f32_16x16x32_bf16(af[i], bfv[j], acc[i][j], 0, 0, 0);
        __syncthreads();
    }

    const int rb = m0 + wm * 64 + lg * 4;
    const int cb = n0 + wn * 64 + lm;
    #pragma unroll
    for (int i = 0; i < 4; i++)
        #pragma unroll
        for (int j = 0; j < 4; j++)
            #pragma unroll
            for (int r = 0; r < 4; r++) {
                int row = rb + i * 16 + r;
                int col = cb + j * 16;
                float v = acc[i][j][r];
                if (EPI == 0) {
                    float val = v + aux1[col];
                    if (col < 256) val *= 0.0625f;          // fold attn scale into Q
                    ((u16*)Cp)[(size_t)row * ldc + col] = f2bf(val);
                } else {
                    size_t idx = (size_t)z * sC + (size_t)row * ldc + col;
                    ((float*)Cp)[idx] = v + aux1[row] + aux2[idx];
                }
            }
}

// ---------------- V transpose: qkv[tok][512+c] -> vt[b][c][n] ----------------
__global__ __launch_bounds__(256) void transpose_v(const u16* __restrict__ qkv,
                                                   u16* __restrict__ vt) {
    int n0 = blockIdx.x * 32, c0 = blockIdx.y * 32, b = blockIdx.z;
    __shared__ u16 tile[32][33];
    int t = threadIdx.x;
    int r = t >> 3, q = t & 7;
    const u16* src = qkv + (size_t)(b * 1024 + n0 + r) * 768 + 512 + c0 + q * 4;
    s4_t v = *(const s4_t*)src;
    #pragma unroll
    for (int j = 0; j < 4; j++) tile[r][q * 4 + j] = (u16)v[j];
    __syncthreads();
    u16* dst = vt + (size_t)b * 262144 + (size_t)(c0 + r) * 1024 + n0 + q * 4;
    s4_t o;
    #pragma unroll
    for (int j = 0; j < 4; j++) o[j] = (short)tile[q * 4 + j][r];
    *(s4_t*)dst = o;
}

// ---------------- flash attention, swapped-operand 32x32 MFMA, K in registers ----------------
// grid 256 = (b, qb) XCD-swizzled; 512 threads = 8 waves = (qw 2) x (dw 2) x (g 2).
// K tile [32 kv][256 c] loaded global->reg per wave (T16); V staged in LDS (dbuf).
__global__ __launch_bounds__(512, 1) void flash_kernel(const u16* __restrict__ qkv,
                                                       const u16* __restrict__ vt,
                                                       u16* __restrict__ O) {
    __shared__ u16 V_lds[2][2][256 * 32];   // [g][buf][d][kv] slot-swizzled, 64 KB
    __shared__ u16 bounce_s[4][32 * 136];   // epilogue store-coalesce, 34.8 KB
    __shared__ float mstat[2][32], lstat[2][32];

    const int flat = blockIdx.x;
    const int xcd = flat & 7, idx = flat >> 3;
    const int b = (xcd << 1) | (idx & 1);     // 2 batches per XCD -> KV fits L2
    const int qb = idx >> 3 == 0 ? idx >> 1 : idx >> 1;  // idx>>1
    const int tid = threadIdx.x;
    const int wv = tid >> 6, lane = tid & 63;
    const int hi = lane >> 5, lq = lane & 31;
    const int qw = wv & 1, dw = (wv >> 1) & 1, g = wv >> 2;

    // Q B-fragments: col=q=lq, chunk tc covers c = tc*16 + hi*8 + e
    const int qrow = qb * 64 + qw * 32 + lq;
    const u16* qptr = qkv + (size_t)(b * 1024 + qrow) * 768 + hi * 8;
    bf8_t qf[16];
    #pragma unroll
    for (int tc = 0; tc < 16; tc++) qf[tc] = *(const bf8_t*)(qptr + tc * 16);

    // K A-fragments for current tile, global->reg (row=kv=lq, c chunk tc*16+hi*8)
    const u16* kp = qkv + (size_t)(b * 1024 + g * 512 + lq) * 768 + 256 + hi * 8;
    bf8_t kreg[16];
    #pragma unroll
    for (int tc = 0; tc < 16; tc++) kreg[tc] = *(const bf8_t*)(kp + tc * 16);
    kp += 32 * 768;

    float m_r = -1e30f, l_r = 0.f;
    f16x_t o_acc[4];
    #pragma unroll
    for (int dt = 0; dt < 4; dt++) o_acc[dt] = (f16x_t)0.0f;

    // V staging: physical slot = logical ^ swz(row), swz = (row&3)^((row>>2)&1)
#define STAGEV(T, BUF)                                                                    \
    {                                                                                     \
        _Pragma("unroll")                                                                 \
        for (int g2 = 0; g2 < 2; g2++) {                                                  \
            _Pragma("unroll")                                                             \
            for (int it = 0; it < 2; it++) {                                              \
                int cid = it * 512 + tid;                                                 \
                int row = cid >> 2, sl = cid & 3;                                         \
                int swz = (row & 3) ^ ((row >> 2) & 1);                                   \
                const u16* gv = vt + (size_t)b * 262144 + (size_t)row * 1024              \
                                    + g2 * 512 + (T) * 32 + ((sl ^ swz) << 3);            \
                GLOAD16(gv, &V_lds[g2][BUF][cid * 8]);                                    \
            }                                                                             \
        }                                                                                 \
    }

    STAGEV(0, 0);
    __syncthreads();

    for (int t = 0; t < 16; ++t) {
        const int buf = t & 1;
        if (t < 15) STAGEV(t + 1, buf ^ 1);

        // ---- QK^T: S^T[32kv][32q] = sum_c K[kv][c] Q[q][c], K from registers ----
        f16x_t s = (f16x_t)0.0f;
        __builtin_amdgcn_s_setprio(1);
        #pragma unroll
        for (int tc = 0; tc < 16; tc++)
            s = __builtin_amdgcn_mfma_f32_32x32x16_bf16(kreg[tc], qf[tc], s, 0, 0, 0);
        __builtin_amdgcn_s_setprio(0);

        // prefetch next K tile into registers (hides L2 latency under softmax+PV)
        if (t < 15) {
            #pragma unroll
            for (int tc = 0; tc < 16; tc++) kreg[tc] = *(const bf8_t*)(kp + tc * 16);
            kp += 32 * 768;
        }

        // ---- lane-local online softmax (lane's q = lq; kv split across hi) ----
        float pm = s[0];
        #pragma unroll
        for (int r = 1; r < 16; r++) pm = fmaxf(pm, s[r]);
        float tm = fmaxf(pm, __shfl_xor(pm, 32));
        if (__ballot(tm > m_r + 8.0f)) {          // defer-max THR=8 (T13)
            float mn = fmaxf(m_r, tm);
            float corr = __expf(m_r - mn);
            m_r = mn; l_r *= corr;
            #pragma unroll
            for (int dt = 0; dt < 4; dt++)
                #pragma unroll
                for (int r = 0; r < 16; r++) o_acc[dt][r] *= corr;
        }
        float p[16], sum = 0.f;
        #pragma unroll
        for (int r = 0; r < 16; r++) { p[r] = __expf(s[r] - m_r); sum += p[r]; }
        l_r += sum;

        // ---- pack P^T B-fragments: position (hi,e) of chunk c2 holds kv=c2*16+hi*8+e
        // own regs: kv(r) = (r&3) + 8*(r>>2) + 4*hi
        unsigned pw[8];
        #pragma unroll
        for (int j = 0; j < 8; j++) pw[j] = cvt_pk_bf16(p[2 * j], p[2 * j + 1]);
        unsigned px[8];
        #pragma unroll
        for (int j = 0; j < 8; j++) px[j] = __shfl_xor((int)pw[j], 32);
        union { unsigned w[4]; bf8_t v; } f0, f1;
        if (hi == 0) {
            f0.w[0] = pw[0]; f0.w[1] = pw[1]; f0.w[2] = px[0]; f0.w[3] = px[1];
            f1.w[0] = pw[4]; f1.w[1] = pw[5]; f1.w[2] = px[4]; f1.w[3] = px[5];
        } else {
            f0.w[0] = px[2]; f0.w[1] = px[3]; f0.w[2] = pw[2]; f0.w[3] = pw[3];
            f1.w[0] = px[6]; f1.w[1] = px[7]; f1.w[2] = pw[6]; f1.w[3] = pw[7];
        }

        // ---- PV: O^T[d][q] += V^T[d][kv] P^T[kv][q] ----
        const char* vb = (const char*)&V_lds[g][buf][0];
        __builtin_amdgcn_s_setprio(1);
        #pragma unroll
        for (int dt = 0; dt < 4; dt++) {
            int vrow = dw * 128 + dt * 32 + lq;
            int swz = (vrow & 3) ^ ((vrow >> 2) & 1);
            bf8_t v0 = *(const bf8_t*)(vb + vrow * 64 + ((hi ^ swz) << 4));
            bf8_t v1 = *(const bf8_t*)(vb + vrow * 64 + (((2 + hi) ^ swz) << 4));
            o_acc[dt] = __builtin_amdgcn_mfma_f32_32x32x16_bf16(v0, f0.v, o_acc[dt], 0, 0, 0);
            o_acc[dt] = __builtin_amdgcn_mfma_f32_32x32x16_bf16(v1, f1.v, o_acc[dt], 0, 0, 0);
        }
        __builtin_amdgcn_s_setprio(0);
        __syncthreads();   // prefetch landed + all waves done with buf
    }

    // ---- merge kv-group partials, normalize, write O[tok][c] ----
    float l_tot = l_r + __shfl_xor(l_r, 32);
    float* obuf = (float*)&V_lds[0][0][0];               // 4 x 4096 f32 = 64 KB
    float* rb = obuf + (qw * 2 + dw) * 4096;
    if (g == 1) {
        #pragma unroll
        for (int dt = 0; dt < 4; dt++)
            #pragma unroll
            for (int r = 0; r < 16; r++) {
                int drow = dt * 32 + (r & 3) + 8 * (r >> 2) + 4 * hi;
                rb[drow * 32 + lq] = o_acc[dt][r];
            }
        if (dw == 0 && hi == 0) { mstat[qw][lq] = m_r; lstat[qw][lq] = l_tot; }
    }
    __syncthreads();
    if (g == 0) {
        float m1 = mstat[qw][lq], l1 = lstat[qw][lq];
        float mm = fmaxf(m_r, m1);
        float a0 = __expf(m_r - mm), a1 = __expf(m1 - mm);
        float inv = 1.0f / (a0 * l_tot + a1 * l1);
        u16* bounce = bounce_s[qw * 2 + dw];
        #pragma unroll
        for (int dt = 0; dt < 4; dt++)
            #pragma unroll
            for (int r = 0; r < 16; r++) {
                int drow = dt * 32 + (r & 3) + 8 * (r >> 2) + 4 * hi;
                float val = (a0 * o_acc[dt][r] + a1 * rb[drow * 32 + lq]) * inv;
                bounce[lq * 136 + drow] = f2bf(val);
            }
        asm volatile("s_waitcnt lgkmcnt(0)" ::: "memory");
        #pragma unroll
        for (int it = 0; it < 4; it++) {
            int qloc = it * 8 + (lane >> 3);
            int dch = (lane & 7) * 16;
            bf8_t lo8 = *(const bf8_t*)&bounce[qloc * 136 + dch];
            bf8_t hi8 = *(const bf8_t*)&bounce[qloc * 136 + dch + 8];
            u16* dst = O + (size_t)(b * 1024 + qb * 64 + qw * 32 + qloc) * 256 + dw * 128 + dch;
            *(bf8_t*)dst = lo8;
            *(bf8_t*)(dst + 8) = hi8;
        }
    }
#undef STAGEV
}

extern "C" void kernel_launch(void* const* d_in, const int* in_sizes, int n_in,
                              void* d_out, int out_size, void* d_ws, size_t ws_size,
                              hipStream_t stream) {
    (void)in_sizes; (void)n_in; (void)out_size; (void)ws_size;
    const float* x   = (const float*)d_in[0];
    const float* lnw = (const float*)d_in[1];
    const float* lnb = (const float*)d_in[2];
    const float* wq  = (const float*)d_in[3];
    const float* bq  = (const float*)d_in[4];
    const float* wk  = (const float*)d_in[5];
    const float* bk  = (const float*)d_in[6];
    const float* wv  = (const float*)d_in[7];
    const float* bv  = (const float*)d_in[8];
    const float* wp  = (const float*)d_in[9];
    const float* bp  = (const float*)d_in[10];
    float* out = (float*)d_out;

    char* ws = (char*)d_ws;
    u16*   wcat  = (u16*)(ws);              // 768*256 bf16
    u16*   wpb   = (u16*)(ws + 0x60000);    // 256*256 bf16
    float* biasc = (float*)(ws + 0x80000);  // 768 f32
    u16*   hn    = (u16*)(ws + 0x90000);    // 16384*256 bf16   (8MB)
    u16*   qkv   = (u16*)(ws + 0x890000);   // 16384*768 bf16   (24MB)
    u16*   vt    = (u16*)(ws + 0x2090000);  // 16*256*1024 bf16 (8MB)
    u16*   O     = (u16*)(ws + 0x2890000);  // 16384*256 bf16   (8MB)

    prep_kernel<<<1028, 256, 0, stream>>>(wq, wk, wv, wp, bq, bk, bv, wcat, wpb, biasc);
    ln_kernel<<<256, 512, 0, stream>>>(x, lnw, lnb, hn);
    // QKV: [16384,768] = hn[16384,256] x wcat[768,256]^T  (+bias, Q*1/16, bf16)
    gemm_bt<0><<<dim3(128, 6, 1), 256, 0, stream>>>(hn, wcat, qkv, 256, 256, 768, 8,
                                                    0, 0, 0, biasc, nullptr);
    transpose_v<<<dim3(32, 8, 16), 256, 0, stream>>>(qkv, vt);
    // fused attention (swapped-operand, K in registers, lane-local softmax)
    flash_kernel<<<256, 512, 0, stream>>>(qkv, vt, O);
    // out[b] = wp x O[b]^T + bp + x  (f32)
    gemm_bt<3><<<dim3(2, 8, 16), 256, 0, stream>>>(wpb, O, out, 256, 256, 1024, 8,
                                                   0, 262144, 262144, bp, x);
}

// Round 6
// 91.985 us; speedup vs baseline: 1.3750x; 1.3750x over previous
//
#include <hip/hip_runtime.h>
#include <hip/hip_bf16.h>
#include <stdint.h>

typedef __attribute__((ext_vector_type(8))) short bf8_t;    // 8 bf16 in 4 VGPRs
typedef __attribute__((ext_vector_type(4))) short s4_t;
typedef __attribute__((ext_vector_type(4))) float f4_t;
typedef __attribute__((ext_vector_type(16))) float f16x_t;  // 32x32 mfma acc
typedef unsigned short u16;

#define GLOAD16(g, l) __builtin_amdgcn_global_load_lds(                                  \
    (const __attribute__((address_space(1))) void*)(g),                                  \
    (__attribute__((address_space(3))) void*)(l), 16, 0, 0)

__device__ __forceinline__ u16 f2bf(float f) {
    union { float f; unsigned u; } c; c.f = f;
    unsigned u = c.u;
    return (u16)((u + 0x7fffu + ((u >> 16) & 1u)) >> 16);   // RNE, inputs finite
}

__device__ __forceinline__ unsigned cvt_pk_bf16(float lo, float hi_) {
    unsigned r;
    asm("v_cvt_pk_bf16_f32 %0, %1, %2" : "=v"(r) : "v"(lo), "v"(hi_));
    return r;                                                // lo -> bits[15:0]
}

// ---------------- weights -> bf16 ----------------
__global__ void prep_kernel(const float* __restrict__ wq, const float* __restrict__ wk,
                            const float* __restrict__ wv, const float* __restrict__ wp,
                            const float* __restrict__ bq, const float* __restrict__ bk,
                            const float* __restrict__ bv,
                            u16* __restrict__ wcat, u16* __restrict__ wpb,
                            float* __restrict__ biasc) {
    int idx = blockIdx.x * 256 + threadIdx.x;
    if (idx < 196608) {                 // wcat [768][256]
        int o = idx >> 8, c = idx & 255;
        float v = (o < 256) ? wq[o * 256 + c]
                : (o < 512) ? wk[(o - 256) * 256 + c]
                            : wv[(o - 512) * 256 + c];
        wcat[idx] = f2bf(v);
    } else if (idx < 262144) {          // wp [256][256]
        wpb[idx - 196608] = f2bf(wp[idx - 196608]);
    } else if (idx < 262912) {          // bias concat [768]
        int i = idx - 262144;
        biasc[i] = (i < 256) ? bq[i] : (i < 512) ? bk[i - 256] : bv[i - 512];
    }
}

// ---------------- LayerNorm over C, single-pass ----------------
__global__ __launch_bounds__(512) void ln_kernel(const float* __restrict__ x,
                                                 const float* __restrict__ lw,
                                                 const float* __restrict__ lb,
                                                 u16* __restrict__ hn) {
    int tid = threadIdx.x;
    int tl = tid & 63, cg = tid >> 6;
    int tok = blockIdx.x * 64 + tl;
    int b = tok >> 10, n = tok & 1023;
    const float* xb = x + (size_t)b * 262144 + n;     // stride 1024 over c
    int ch0 = cg * 32;
    float v[32];
    float s = 0.f, s2 = 0.f;
    #pragma unroll
    for (int j = 0; j < 32; j++) {
        v[j] = xb[(size_t)(ch0 + j) * 1024];
        s += v[j]; s2 += v[j] * v[j];
    }
    __shared__ float2 red[8][64];
    red[cg][tl] = make_float2(s, s2);
    __syncthreads();
    s = 0.f; s2 = 0.f;
    #pragma unroll
    for (int g = 0; g < 8; g++) { float2 p = red[g][tl]; s += p.x; s2 += p.y; }
    float mean = s * 0.00390625f;
    float var  = s2 * 0.00390625f - mean * mean;
    float rstd = rsqrtf(var + 1e-6f);
    u16* hr = hn + (size_t)tok * 256 + ch0;
    #pragma unroll
    for (int j8 = 0; j8 < 4; j8++) {
        bf8_t pk;
        #pragma unroll
        for (int j = 0; j < 8; j++) {
            int c = j8 * 8 + j;
            float y = (v[c] - mean) * rstd * lw[ch0 + c] + lb[ch0 + c];
            pk[j] = (short)f2bf(y);
        }
        *(bf8_t*)&hr[j8 * 8] = pk;
    }
}

// ---------------- generic B^T bf16 GEMM, 128x128 tile, m97 structure ----------------
// EPI: 0 = QKV (+bias, Q scaled by 1/16, bf16 out)   3 = PROJ (+bias + residual, f32 out)
template <int EPI>
__global__ __launch_bounds__(256, 2) void gemm_bt(
    const u16* __restrict__ A, const u16* __restrict__ B, void* __restrict__ Cp,
    int lda, int ldb, int ldc, int nk,
    long sA, long sB, long sC,
    const float* __restrict__ aux1, const float* __restrict__ aux2) {
    __shared__ u16 lsA[128 * 32];
    __shared__ u16 lsB[128 * 32];
    const int tid = threadIdx.x;
    const int z = blockIdx.z;
    const int m0 = blockIdx.x * 128, n0 = blockIdx.y * 128;
    const int lane = tid & 63;
    const int w = tid >> 6, wm = w >> 1, wn = w & 1;
    const int lm = lane & 15, lg = lane >> 4;
    const int sr = tid >> 2, sc = (tid & 3) * 8;

    const u16* ga = A + (size_t)z * sA + (size_t)(m0 + sr) * lda + sc;
    const u16* gb = B + (size_t)z * sB + (size_t)(n0 + sr) * ldb + sc;
    u16* la  = &lsA[sr * 32 + sc];
    u16* lb2 = &lsB[sr * 32 + sc];

    f4_t acc[4][4];
    #pragma unroll
    for (int i = 0; i < 4; i++)
        #pragma unroll
        for (int j = 0; j < 4; j++) acc[i][j] = (f4_t)0.0f;

    for (int kt = 0; kt < nk; ++kt) {
        GLOAD16(ga, la);
        GLOAD16(ga + (size_t)64 * lda, la + 64 * 32);
        GLOAD16(gb, lb2);
        GLOAD16(gb + (size_t)64 * ldb, lb2 + 64 * 32);
        ga += 32; gb += 32;
        __syncthreads();
        bf8_t af[4], bfv[4];
        #pragma unroll
        for (int i = 0; i < 4; i++)
            af[i] = *(const bf8_t*)&lsA[(wm * 64 + i * 16 + lm) * 32 + lg * 8];
        #pragma unroll
        for (int i = 0; i < 4; i++)
            bfv[i] = *(const bf8_t*)&lsB[(wn * 64 + i * 16 + lm) * 32 + lg * 8];
        #pragma unroll
        for (int i = 0; i < 4; i++)
            #pragma unroll
            for (int j = 0; j < 4; j++)
                acc[i][j] = __builtin_amdgcn_mfma_f32_16x16x32_bf16(af[i], bfv[j], acc[i][j], 0, 0, 0);
        __syncthreads();
    }

    const int rb = m0 + wm * 64 + lg * 4;
    const int cb = n0 + wn * 64 + lm;
    #pragma unroll
    for (int i = 0; i < 4; i++)
        #pragma unroll
        for (int j = 0; j < 4; j++)
            #pragma unroll
            for (int r = 0; r < 4; r++) {
                int row = rb + i * 16 + r;
                int col = cb + j * 16;
                float v = acc[i][j][r];
                if (EPI == 0) {
                    float val = v + aux1[col];
                    if (col < 256) val *= 0.0625f;          // fold attn scale into Q
                    ((u16*)Cp)[(size_t)row * ldc + col] = f2bf(val);
                } else {
                    size_t idx = (size_t)z * sC + (size_t)row * ldc + col;
                    ((float*)Cp)[idx] = v + aux1[row] + aux2[idx];
                }
            }
}

// ---------------- V transpose: qkv[tok][512+c] -> vt[b][c][n] ----------------
__global__ __launch_bounds__(256) void transpose_v(const u16* __restrict__ qkv,
                                                   u16* __restrict__ vt) {
    int n0 = blockIdx.x * 32, c0 = blockIdx.y * 32, b = blockIdx.z;
    __shared__ u16 tile[32][33];
    int t = threadIdx.x;
    int r = t >> 3, q = t & 7;
    const u16* src = qkv + (size_t)(b * 1024 + n0 + r) * 768 + 512 + c0 + q * 4;
    s4_t v = *(const s4_t*)src;
    #pragma unroll
    for (int j = 0; j < 4; j++) tile[r][q * 4 + j] = (u16)v[j];
    __syncthreads();
    u16* dst = vt + (size_t)b * 262144 + (size_t)(c0 + r) * 1024 + n0 + q * 4;
    s4_t o;
    #pragma unroll
    for (int j = 0; j < 4; j++) o[j] = (short)tile[q * 4 + j][r];
    *(s4_t*)dst = o;
}

// ---------------- flash attention, swapped-operand 32x32 MFMA ----------------
// grid 256 = (b, qb) XCD-swizzled; 512 threads = 8 waves = (qw 2) x (dw 2) x (g 2).
// K+V staged in LDS (dbuf, coalesced global_load_lds); fragment loads batched
// into register arrays (kf[16]/vf[8]) so ds_read latency amortizes; 256-VGPR
// budget forced via amdgpu_waves_per_eu(2,2).
__global__ __launch_bounds__(512)
__attribute__((amdgpu_waves_per_eu(2, 2)))
void flash_kernel(const u16* __restrict__ qkv,
                  const u16* __restrict__ vt,
                  u16* __restrict__ O) {
    __shared__ u16 K_lds[2][2][32 * 256];   // [g][buf][kv][c] slot-swizzled, 64 KB
    __shared__ u16 V_lds[2][2][256 * 32];   // [g][buf][d][kv] slot-swizzled, 64 KB
    __shared__ float mstat[2][32], lstat[2][32];

    const int flat = blockIdx.x;
    const int xcd = flat & 7, idx = flat >> 3;
    const int b = (xcd << 1) | (idx & 1);     // 2 batches per XCD -> KV fits L2
    const int qb = idx >> 1;
    const int tid = threadIdx.x;
    const int wv = tid >> 6, lane = tid & 63;
    const int hi = lane >> 5, lq = lane & 31;
    const int qw = wv & 1, dw = (wv >> 1) & 1, g = wv >> 2;

    // Q B-fragments: col=q=lq, chunk tc covers c = tc*16 + hi*8 + e
    const int qrow = qb * 64 + qw * 32 + lq;
    const u16* qptr = qkv + (size_t)(b * 1024 + qrow) * 768 + hi * 8;
    bf8_t qf[16];
    #pragma unroll
    for (int tc = 0; tc < 16; tc++) qf[tc] = *(const bf8_t*)(qptr + tc * 16);

    float m_r = -1e30f, l_r = 0.f;
    f16x_t o_acc[4];
    #pragma unroll
    for (int dt = 0; dt < 4; dt++) o_acc[dt] = (f16x_t)0.0f;

    // K staging: row-linear LDS, global column pre-permuted (slot ^ (row&7))
    // V staging: slot ^ swz(row), swz = (row&3)^((row>>2)&1)  (conflict-free reads)
#define STAGE(T, BUF)                                                                     \
    {                                                                                     \
        _Pragma("unroll")                                                                 \
        for (int g2 = 0; g2 < 2; g2++) {                                                  \
            _Pragma("unroll")                                                             \
            for (int it = 0; it < 2; it++) {                                              \
                int cid = it * 512 + tid;                                                 \
                int row = cid >> 5, sl = cid & 31;                                        \
                const u16* gk = qkv + (size_t)(b * 1024 + g2 * 512 + (T) * 32 + row) * 768\
                                    + 256 + ((sl ^ (row & 7)) << 3);                      \
                GLOAD16(gk, &K_lds[g2][BUF][cid * 8]);                                    \
            }                                                                             \
            _Pragma("unroll")                                                             \
            for (int it = 0; it < 2; it++) {                                              \
                int cid = it * 512 + tid;                                                 \
                int row = cid >> 2, sl = cid & 3;                                         \
                int swz = (row & 3) ^ ((row >> 2) & 1);                                   \
                const u16* gv = vt + (size_t)b * 262144 + (size_t)row * 1024              \
                                    + g2 * 512 + (T) * 32 + ((sl ^ swz) << 3);            \
                GLOAD16(gv, &V_lds[g2][BUF][cid * 8]);                                    \
            }                                                                             \
        }                                                                                 \
    }

    STAGE(0, 0);
    __syncthreads();

    for (int t = 0; t < 16; ++t) {
        const int buf = t & 1;
        if (t < 15) STAGE(t + 1, buf ^ 1);

        // ---- QK^T: S^T[32kv][32q] = sum_c K[kv][c] Q[q][c] ----
        // batch all 16 K fragments first (latency amortized), then 2 MFMA chains
        const char* kb = (const char*)&K_lds[g][buf][0];
        bf8_t kf[16];
        #pragma unroll
        for (int tc = 0; tc < 16; tc++)
            kf[tc] = *(const bf8_t*)(kb + lq * 512 + (((tc * 2 + hi) ^ (lq & 7)) << 4));
        f16x_t s0 = (f16x_t)0.0f, s1 = (f16x_t)0.0f;
        __builtin_amdgcn_s_setprio(1);
        #pragma unroll
        for (int tc = 0; tc < 8; tc++) {
            s0 = __builtin_amdgcn_mfma_f32_32x32x16_bf16(kf[2 * tc],     qf[2 * tc],     s0, 0, 0, 0);
            s1 = __builtin_amdgcn_mfma_f32_32x32x16_bf16(kf[2 * tc + 1], qf[2 * tc + 1], s1, 0, 0, 0);
        }
        __builtin_amdgcn_s_setprio(0);
        f16x_t s = s0 + s1;

        // ---- lane-local online softmax (lane's q = lq; kv split across hi) ----
        float m01 = fmaxf(s[0], s[1]),   m23 = fmaxf(s[2], s[3]);
        float m45 = fmaxf(s[4], s[5]),   m67 = fmaxf(s[6], s[7]);
        float m89 = fmaxf(s[8], s[9]),   mab = fmaxf(s[10], s[11]);
        float mcd = fmaxf(s[12], s[13]), mef = fmaxf(s[14], s[15]);
        float pm = fmaxf(fmaxf(fmaxf(m01, m23), fmaxf(m45, m67)),
                         fmaxf(fmaxf(m89, mab), fmaxf(mcd, mef)));
        float tm = fmaxf(pm, __shfl_xor(pm, 32));
        if (__ballot(tm > m_r + 8.0f)) {          // defer-max THR=8 (T13)
            float mn = fmaxf(m_r, tm);
            float corr = __expf(m_r - mn);
            m_r = mn; l_r *= corr;
            #pragma unroll
            for (int dt = 0; dt < 4; dt++)
                #pragma unroll
                for (int r = 0; r < 16; r++) o_acc[dt][r] *= corr;
        }
        float p[16], sum = 0.f;
        #pragma unroll
        for (int r = 0; r < 16; r++) { p[r] = __expf(s[r] - m_r); sum += p[r]; }
        l_r += sum;

        // ---- pack P^T B-fragments: position (hi,e) of chunk c2 holds kv=c2*16+hi*8+e
        // own regs: kv(r) = (r&3) + 8*(r>>2) + 4*hi
        unsigned pw[8];
        #pragma unroll
        for (int j = 0; j < 8; j++) pw[j] = cvt_pk_bf16(p[2 * j], p[2 * j + 1]);
        unsigned px[8];
        #pragma unroll
        for (int j = 0; j < 8; j++) px[j] = __shfl_xor((int)pw[j], 32);
        union { unsigned w[4]; bf8_t v; } f0, f1;
        if (hi == 0) {
            f0.w[0] = pw[0]; f0.w[1] = pw[1]; f0.w[2] = px[0]; f0.w[3] = px[1];
            f1.w[0] = pw[4]; f1.w[1] = pw[5]; f1.w[2] = px[4]; f1.w[3] = px[5];
        } else {
            f0.w[0] = px[2]; f0.w[1] = px[3]; f0.w[2] = pw[2]; f0.w[3] = pw[3];
            f1.w[0] = px[6]; f1.w[1] = px[7]; f1.w[2] = pw[6]; f1.w[3] = pw[7];
        }

        // ---- PV: O^T[d][q] += V^T[d][kv] P^T[kv][q], V fragments batched ----
        const char* vb = (const char*)&V_lds[g][buf][0];
        bf8_t vf[8];
        #pragma unroll
        for (int dt = 0; dt < 4; dt++) {
            int vrow = dw * 128 + dt * 32 + lq;
            int swz = (vrow & 3) ^ ((vrow >> 2) & 1);
            vf[2 * dt]     = *(const bf8_t*)(vb + vrow * 64 + ((hi ^ swz) << 4));
            vf[2 * dt + 1] = *(const bf8_t*)(vb + vrow * 64 + (((2 + hi) ^ swz) << 4));
        }
        __builtin_amdgcn_s_setprio(1);
        #pragma unroll
        for (int dt = 0; dt < 4; dt++) {
            o_acc[dt] = __builtin_amdgcn_mfma_f32_32x32x16_bf16(vf[2 * dt],     f0.v, o_acc[dt], 0, 0, 0);
            o_acc[dt] = __builtin_amdgcn_mfma_f32_32x32x16_bf16(vf[2 * dt + 1], f1.v, o_acc[dt], 0, 0, 0);
        }
        __builtin_amdgcn_s_setprio(0);
        __syncthreads();   // prefetch landed + all waves done with buf
    }

    // ---- merge kv-group partials, normalize, write O[tok][c] ----
    float l_tot = l_r + __shfl_xor(l_r, 32);
    float* obuf = (float*)&K_lds[0][0][0];               // 4 x 4096 f32 = 64 KB
    float* rb = obuf + (qw * 2 + dw) * 4096;
    if (g == 1) {
        #pragma unroll
        for (int dt = 0; dt < 4; dt++)
            #pragma unroll
            for (int r = 0; r < 16; r++) {
                int drow = dt * 32 + (r & 3) + 8 * (r >> 2) + 4 * hi;
                rb[drow * 32 + lq] = o_acc[dt][r];
            }
        if (dw == 0 && hi == 0) { mstat[qw][lq] = m_r; lstat[qw][lq] = l_tot; }
    }
    __syncthreads();
    if (g == 0) {
        float m1 = mstat[qw][lq], l1 = lstat[qw][lq];
        float mm = fmaxf(m_r, m1);
        float a0 = __expf(m_r - mm), a1 = __expf(m1 - mm);
        float inv = 1.0f / (a0 * l_tot + a1 * l1);
        u16* bounce = (u16*)&V_lds[0][0][0] + (qw * 2 + dw) * (32 * 136);
        #pragma unroll
        for (int dt = 0; dt < 4; dt++)
            #pragma unroll
            for (int r = 0; r < 16; r++) {
                int drow = dt * 32 + (r & 3) + 8 * (r >> 2) + 4 * hi;
                float val = (a0 * o_acc[dt][r] + a1 * rb[drow * 32 + lq]) * inv;
                bounce[lq * 136 + drow] = f2bf(val);
            }
        asm volatile("s_waitcnt lgkmcnt(0)" ::: "memory");
        #pragma unroll
        for (int it = 0; it < 4; it++) {
            int qloc = it * 8 + (lane >> 3);
            int dch = (lane & 7) * 16;
            bf8_t lo8 = *(const bf8_t*)&bounce[qloc * 136 + dch];
            bf8_t hi8 = *(const bf8_t*)&bounce[qloc * 136 + dch + 8];
            u16* dst = O + (size_t)(b * 1024 + qb * 64 + qw * 32 + qloc) * 256 + dw * 128 + dch;
            *(bf8_t*)dst = lo8;
            *(bf8_t*)(dst + 8) = hi8;
        }
    }
#undef STAGE
}

extern "C" void kernel_launch(void* const* d_in, const int* in_sizes, int n_in,
                              void* d_out, int out_size, void* d_ws, size_t ws_size,
                              hipStream_t stream) {
    (void)in_sizes; (void)n_in; (void)out_size; (void)ws_size;
    const float* x   = (const float*)d_in[0];
    const float* lnw = (const float*)d_in[1];
    const float* lnb = (const float*)d_in[2];
    const float* wq  = (const float*)d_in[3];
    const float* bq  = (const float*)d_in[4];
    const float* wk  = (const float*)d_in[5];
    const float* bk  = (const float*)d_in[6];
    const float* wv  = (const float*)d_in[7];
    const float* bv  = (const float*)d_in[8];
    const float* wp  = (const float*)d_in[9];
    const float* bp  = (const float*)d_in[10];
    float* out = (float*)d_out;

    char* ws = (char*)d_ws;
    u16*   wcat  = (u16*)(ws);              // 768*256 bf16
    u16*   wpb   = (u16*)(ws + 0x60000);    // 256*256 bf16
    float* biasc = (float*)(ws + 0x80000);  // 768 f32
    u16*   hn    = (u16*)(ws + 0x90000);    // 16384*256 bf16   (8MB)
    u16*   qkv   = (u16*)(ws + 0x890000);   // 16384*768 bf16   (24MB)
    u16*   vt    = (u16*)(ws + 0x2090000);  // 16*256*1024 bf16 (8MB)
    u16*   O     = (u16*)(ws + 0x2890000);  // 16384*256 bf16   (8MB)

    prep_kernel<<<1028, 256, 0, stream>>>(wq, wk, wv, wp, bq, bk, bv, wcat, wpb, biasc);
    ln_kernel<<<256, 512, 0, stream>>>(x, lnw, lnb, hn);
    // QKV: [16384,768] = hn[16384,256] x wcat[768,256]^T  (+bias, Q*1/16, bf16)
    gemm_bt<0><<<dim3(128, 6, 1), 256, 0, stream>>>(hn, wcat, qkv, 256, 256, 768, 8,
                                                    0, 0, 0, biasc, nullptr);
    transpose_v<<<dim3(32, 8, 16), 256, 0, stream>>>(qkv, vt);
    // fused attention (swapped-operand, K+V LDS, batched fragment loads)
    flash_kernel<<<256, 512, 0, stream>>>(qkv, vt, O);
    // out[b] = wp x O[b]^T + bp + x  (f32)
    gemm_bt<3><<<dim3(2, 8, 16), 256, 0, stream>>>(wpb, O, out, 256, 256, 1024, 8,
                                                   0, 262144, 262144, bp, x);
}

// Round 7
// 85.114 us; speedup vs baseline: 1.4860x; 1.0807x over previous
//
#include <hip/hip_runtime.h>
#include <hip/hip_bf16.h>
#include <stdint.h>

typedef __attribute__((ext_vector_type(8))) short bf8_t;    // 8 bf16 in 4 VGPRs
typedef __attribute__((ext_vector_type(4))) short s4_t;
typedef __attribute__((ext_vector_type(4))) float f4_t;
typedef __attribute__((ext_vector_type(16))) float f16x_t;  // 32x32 mfma acc
typedef unsigned short u16;

#define GLOAD16(g, l) __builtin_amdgcn_global_load_lds(                                  \
    (const __attribute__((address_space(1))) void*)(g),                                  \
    (__attribute__((address_space(3))) void*)(l), 16, 0, 0)

__device__ __forceinline__ u16 f2bf(float f) {
    union { float f; unsigned u; } c; c.f = f;
    unsigned u = c.u;
    return (u16)((u + 0x7fffu + ((u >> 16) & 1u)) >> 16);   // RNE, inputs finite
}

__device__ __forceinline__ unsigned cvt_pk_bf16(float lo, float hi_) {
    unsigned r;
    asm("v_cvt_pk_bf16_f32 %0, %1, %2" : "=v"(r) : "v"(lo), "v"(hi_));
    return r;                                                // lo -> bits[15:0]
}

// ---------------- weights -> bf16 ----------------
__global__ void prep_kernel(const float* __restrict__ wq, const float* __restrict__ wk,
                            const float* __restrict__ wv, const float* __restrict__ wp,
                            const float* __restrict__ bq, const float* __restrict__ bk,
                            const float* __restrict__ bv,
                            u16* __restrict__ wcat, u16* __restrict__ wpb,
                            float* __restrict__ biasc) {
    int idx = blockIdx.x * 256 + threadIdx.x;
    if (idx < 196608) {                 // wcat [768][256]
        int o = idx >> 8, c = idx & 255;
        float v = (o < 256) ? wq[o * 256 + c]
                : (o < 512) ? wk[(o - 256) * 256 + c]
                            : wv[(o - 512) * 256 + c];
        wcat[idx] = f2bf(v);
    } else if (idx < 262144) {          // wp [256][256]
        wpb[idx - 196608] = f2bf(wp[idx - 196608]);
    } else if (idx < 262912) {          // bias concat [768]
        int i = idx - 262144;
        biasc[i] = (i < 256) ? bq[i] : (i < 512) ? bk[i - 256] : bv[i - 512];
    }
}

// ---------------- LayerNorm over C, single-pass ----------------
__global__ __launch_bounds__(512) void ln_kernel(const float* __restrict__ x,
                                                 const float* __restrict__ lw,
                                                 const float* __restrict__ lb,
                                                 u16* __restrict__ hn) {
    int tid = threadIdx.x;
    int tl = tid & 63, cg = tid >> 6;
    int tok = blockIdx.x * 64 + tl;
    int b = tok >> 10, n = tok & 1023;
    const float* xb = x + (size_t)b * 262144 + n;     // stride 1024 over c
    int ch0 = cg * 32;
    float v[32];
    float s = 0.f, s2 = 0.f;
    #pragma unroll
    for (int j = 0; j < 32; j++) {
        v[j] = xb[(size_t)(ch0 + j) * 1024];
        s += v[j]; s2 += v[j] * v[j];
    }
    __shared__ float2 red[8][64];
    red[cg][tl] = make_float2(s, s2);
    __syncthreads();
    s = 0.f; s2 = 0.f;
    #pragma unroll
    for (int g = 0; g < 8; g++) { float2 p = red[g][tl]; s += p.x; s2 += p.y; }
    float mean = s * 0.00390625f;
    float var  = s2 * 0.00390625f - mean * mean;
    float rstd = rsqrtf(var + 1e-6f);
    u16* hr = hn + (size_t)tok * 256 + ch0;
    #pragma unroll
    for (int j8 = 0; j8 < 4; j8++) {
        bf8_t pk;
        #pragma unroll
        for (int j = 0; j < 8; j++) {
            int c = j8 * 8 + j;
            float y = (v[c] - mean) * rstd * lw[ch0 + c] + lb[ch0 + c];
            pk[j] = (short)f2bf(y);
        }
        *(bf8_t*)&hr[j8 * 8] = pk;
    }
}

// ---------------- generic B^T bf16 GEMM, 128x128 tile, m97 structure ----------------
// EPI 0 = QKV: writes Q (scaled, [tok][256]) / K (kt[b][c>>3][n][8]) / V (vt3[b][n>>3][c][8])
// EPI 3 = PROJ: +bias +residual, f32 out
template <int EPI>
__global__ __launch_bounds__(256, 2) void gemm_bt(
    const u16* __restrict__ A, const u16* __restrict__ B, void* __restrict__ Cp,
    int lda, int ldb, int ldc, int nk,
    long sA, long sB, long sC,
    const float* __restrict__ aux1, const float* __restrict__ aux2,
    u16* __restrict__ ktp, u16* __restrict__ vtp) {
    __shared__ u16 lsA[128 * 32];
    __shared__ u16 lsB[128 * 32];
    const int tid = threadIdx.x;
    const int z = blockIdx.z;
    const int m0 = blockIdx.x * 128, n0 = blockIdx.y * 128;
    const int lane = tid & 63;
    const int w = tid >> 6, wm = w >> 1, wn = w & 1;
    const int lm = lane & 15, lg = lane >> 4;
    const int sr = tid >> 2, sc = (tid & 3) * 8;

    const u16* ga = A + (size_t)z * sA + (size_t)(m0 + sr) * lda + sc;
    const u16* gb = B + (size_t)z * sB + (size_t)(n0 + sr) * ldb + sc;
    u16* la  = &lsA[sr * 32 + sc];
    u16* lb2 = &lsB[sr * 32 + sc];

    f4_t acc[4][4];
    #pragma unroll
    for (int i = 0; i < 4; i++)
        #pragma unroll
        for (int j = 0; j < 4; j++) acc[i][j] = (f4_t)0.0f;

    for (int kt = 0; kt < nk; ++kt) {
        GLOAD16(ga, la);
        GLOAD16(ga + (size_t)64 * lda, la + 64 * 32);
        GLOAD16(gb, lb2);
        GLOAD16(gb + (size_t)64 * ldb, lb2 + 64 * 32);
        ga += 32; gb += 32;
        __syncthreads();
        bf8_t af[4], bfv[4];
        #pragma unroll
        for (int i = 0; i < 4; i++)
            af[i] = *(const bf8_t*)&lsA[(wm * 64 + i * 16 + lm) * 32 + lg * 8];
        #pragma unroll
        for (int i = 0; i < 4; i++)
            bfv[i] = *(const bf8_t*)&lsB[(wn * 64 + i * 16 + lm) * 32 + lg * 8];
        #pragma unroll
        for (int i = 0; i < 4; i++)
            #pragma unroll
            for (int j = 0; j < 4; j++)
                acc[i][j] = __builtin_amdgcn_mfma_f32_16x16x32_bf16(af[i], bfv[j], acc[i][j], 0, 0, 0);
        __syncthreads();
    }

    const int rb = m0 + wm * 64 + lg * 4;
    const int cb = n0 + wn * 64 + lm;
    #pragma unroll
    for (int i = 0; i < 4; i++)
        #pragma unroll
        for (int j = 0; j < 4; j++)
            #pragma unroll
            for (int r = 0; r < 4; r++) {
                int row = rb + i * 16 + r;
                int col = cb + j * 16;
                float v = acc[i][j][r];
                if (EPI == 0) {
                    float val = v + aux1[col];
                    int bb = row >> 10, n = row & 1023;
                    if (col < 256) {            // Q, pre-scaled
                        ((u16*)Cp)[(size_t)row * 256 + col] = f2bf(val * 0.0625f);
                    } else if (col < 512) {     // K -> kt[b][c>>3][n][8]
                        int c = col - 256;
                        ktp[(((size_t)bb * 32 + (c >> 3)) * 1024 + n) * 8 + (c & 7)] = f2bf(val);
                    } else {                    // V -> vt3[b][n>>3][c][8]
                        int d = col - 512;
                        vtp[(((size_t)bb * 128 + (n >> 3)) * 256 + d) * 8 + (n & 7)] = f2bf(val);
                    }
                } else {
                    size_t idx = (size_t)z * sC + (size_t)row * ldc + col;
                    ((float*)Cp)[idx] = v + aux1[row] + aux2[idx];
                }
            }
}

// ---------------- flash attention, swapped-operand 32x32 MFMA ----------------
// grid 256 = (b, qb) XCD-swizzled; 512 threads = 8 waves = (qw 2) x (dw 2) x (g 2).
// Conflict-free LDS layouts: K [chunk 32][kv 32] x16B, V [kc 4][d 256] x16B,
// fed by pre-transposed kt/vt3 (linear global_load_lds, no swizzle needed).
__global__ __launch_bounds__(512)
__attribute__((amdgpu_waves_per_eu(2, 2)))
void flash_kernel(const u16* __restrict__ qbuf,
                  const u16* __restrict__ kt,
                  const u16* __restrict__ vt3,
                  u16* __restrict__ O) {
    __shared__ u16 K_lds[2][2][32 * 32 * 8];   // [g][buf][chunk][kv] 16B units, 64 KB
    __shared__ u16 V_lds[2][2][4 * 256 * 8];   // [g][buf][kc][d]    16B units, 64 KB
    __shared__ float mstat[2][32], lstat[2][32];

    const int flat = blockIdx.x;
    const int xcd = flat & 7, idx = flat >> 3;
    const int b = (xcd << 1) | (idx & 1);     // 2 batches per XCD -> KV fits L2
    const int qb = idx >> 1;
    const int tid = threadIdx.x;
    const int wv = tid >> 6, lane = tid & 63;
    const int hi = lane >> 5, lq = lane & 31;
    const int qw = wv & 1, dw = (wv >> 1) & 1, g = wv >> 2;

    // Q B-fragments: col=q=lq, chunk tc covers c = tc*16 + hi*8 + e
    const int qrow = qb * 64 + qw * 32 + lq;
    const u16* qptr = qbuf + (size_t)(b * 1024 + qrow) * 256 + hi * 8;
    bf8_t qf[16];
    #pragma unroll
    for (int tc = 0; tc < 16; tc++) qf[tc] = *(const bf8_t*)(qptr + tc * 16);

    float m_r = -1e30f, l_r = 0.f;
    f16x_t o_acc[4];
    #pragma unroll
    for (int dt = 0; dt < 4; dt++) o_acc[dt] = (f16x_t)0.0f;

    // K stage: cid -> (chunk = cid>>5, kvl = cid&31); src kt contiguous 512B runs
    // V stage: cid -> (kc = cid>>8, d = cid&255);     src vt3 contiguous 1KB runs
#define STAGE(T, BUF)                                                                     \
    {                                                                                     \
        _Pragma("unroll")                                                                 \
        for (int g2 = 0; g2 < 2; g2++) {                                                  \
            _Pragma("unroll")                                                             \
            for (int it = 0; it < 2; it++) {                                              \
                int cid = it * 512 + tid;                                                 \
                int chunk = cid >> 5, kvl = cid & 31;                                     \
                const u16* gk = kt + (((size_t)b * 32 + chunk) * 1024                     \
                                      + g2 * 512 + (T) * 32 + kvl) * 8;                   \
                GLOAD16(gk, &K_lds[g2][BUF][cid * 8]);                                    \
            }                                                                             \
            _Pragma("unroll")                                                             \
            for (int it = 0; it < 2; it++) {                                              \
                int cid = it * 512 + tid;                                                 \
                int kc = cid >> 8, d = cid & 255;                                         \
                const u16* gv = vt3 + (((size_t)b * 128 + g2 * 64 + (T) * 4 + kc) * 256   \
                                       + d) * 8;                                          \
                GLOAD16(gv, &V_lds[g2][BUF][cid * 8]);                                    \
            }                                                                             \
        }                                                                                 \
    }

    STAGE(0, 0);
    __syncthreads();

    for (int t = 0; t < 16; ++t) {
        const int buf = t & 1;
        if (t < 15) STAGE(t + 1, buf ^ 1);

        // ---- QK^T: S^T[32kv][32q] = sum_c K[kv][c] Q[q][c] ----
        const u16* kb = &K_lds[g][buf][0];
        bf8_t kf[16];
        #pragma unroll
        for (int tc = 0; tc < 16; tc++)
            kf[tc] = *(const bf8_t*)(kb + ((tc * 2 + hi) * 32 + lq) * 8);
        f16x_t s0 = (f16x_t)0.0f, s1 = (f16x_t)0.0f;
        __builtin_amdgcn_s_setprio(1);
        #pragma unroll
        for (int tc = 0; tc < 8; tc++) {
            s0 = __builtin_amdgcn_mfma_f32_32x32x16_bf16(kf[2 * tc],     qf[2 * tc],     s0, 0, 0, 0);
            s1 = __builtin_amdgcn_mfma_f32_32x32x16_bf16(kf[2 * tc + 1], qf[2 * tc + 1], s1, 0, 0, 0);
        }
        __builtin_amdgcn_s_setprio(0);
        f16x_t s = s0 + s1;

        // ---- lane-local online softmax (lane's q = lq; kv split across hi) ----
        float m01 = fmaxf(s[0], s[1]),   m23 = fmaxf(s[2], s[3]);
        float m45 = fmaxf(s[4], s[5]),   m67 = fmaxf(s[6], s[7]);
        float m89 = fmaxf(s[8], s[9]),   mab = fmaxf(s[10], s[11]);
        float mcd = fmaxf(s[12], s[13]), mef = fmaxf(s[14], s[15]);
        float pm = fmaxf(fmaxf(fmaxf(m01, m23), fmaxf(m45, m67)),
                         fmaxf(fmaxf(m89, mab), fmaxf(mcd, mef)));
        float tm = fmaxf(pm, __shfl_xor(pm, 32));
        if (__ballot(tm > m_r + 8.0f)) {          // defer-max THR=8 (T13)
            float mn = fmaxf(m_r, tm);
            float corr = __expf(m_r - mn);
            m_r = mn; l_r *= corr;
            #pragma unroll
            for (int dt = 0; dt < 4; dt++)
                #pragma unroll
                for (int r = 0; r < 16; r++) o_acc[dt][r] *= corr;
        }
        float p[16], sum = 0.f;
        #pragma unroll
        for (int r = 0; r < 16; r++) { p[r] = __expf(s[r] - m_r); sum += p[r]; }
        l_r += sum;

        // ---- pack P^T B-fragments: position (hi,e) of chunk c2 holds kv=c2*16+hi*8+e
        // own regs: kv(r) = (r&3) + 8*(r>>2) + 4*hi
        unsigned pw[8];
        #pragma unroll
        for (int j = 0; j < 8; j++) pw[j] = cvt_pk_bf16(p[2 * j], p[2 * j + 1]);
        unsigned px[8];
        #pragma unroll
        for (int j = 0; j < 8; j++) px[j] = __shfl_xor((int)pw[j], 32);
        union { unsigned w[4]; bf8_t v; } f0, f1;
        if (hi == 0) {
            f0.w[0] = pw[0]; f0.w[1] = pw[1]; f0.w[2] = px[0]; f0.w[3] = px[1];
            f1.w[0] = pw[4]; f1.w[1] = pw[5]; f1.w[2] = px[4]; f1.w[3] = px[5];
        } else {
            f0.w[0] = px[2]; f0.w[1] = px[3]; f0.w[2] = pw[2]; f0.w[3] = pw[3];
            f1.w[0] = px[6]; f1.w[1] = px[7]; f1.w[2] = pw[6]; f1.w[3] = pw[7];
        }

        // ---- PV: O^T[d][q] += V^T[d][kv] P^T[kv][q], V fragments batched ----
        const u16* vb = &V_lds[g][buf][0];
        bf8_t vf[8];
        #pragma unroll
        for (int dt = 0; dt < 4; dt++) {
            int vrow = dw * 128 + dt * 32 + lq;
            vf[2 * dt]     = *(const bf8_t*)(vb + (hi * 256 + vrow) * 8);
            vf[2 * dt + 1] = *(const bf8_t*)(vb + ((2 + hi) * 256 + vrow) * 8);
        }
        __builtin_amdgcn_s_setprio(1);
        #pragma unroll
        for (int dt = 0; dt < 4; dt++) {
            o_acc[dt] = __builtin_amdgcn_mfma_f32_32x32x16_bf16(vf[2 * dt],     f0.v, o_acc[dt], 0, 0, 0);
            o_acc[dt] = __builtin_amdgcn_mfma_f32_32x32x16_bf16(vf[2 * dt + 1], f1.v, o_acc[dt], 0, 0, 0);
        }
        __builtin_amdgcn_s_setprio(0);
        __syncthreads();   // prefetch landed + all waves done with buf
    }

    // ---- merge kv-group partials, normalize, write O[tok][c] ----
    float l_tot = l_r + __shfl_xor(l_r, 32);
    float* obuf = (float*)&K_lds[0][0][0];               // 4 x 4096 f32 = 64 KB
    float* rb = obuf + (qw * 2 + dw) * 4096;
    if (g == 1) {
        #pragma unroll
        for (int dt = 0; dt < 4; dt++)
            #pragma unroll
            for (int r = 0; r < 16; r++) {
                int drow = dt * 32 + (r & 3) + 8 * (r >> 2) + 4 * hi;
                rb[drow * 32 + lq] = o_acc[dt][r];
            }
        if (dw == 0 && hi == 0) { mstat[qw][lq] = m_r; lstat[qw][lq] = l_tot; }
    }
    __syncthreads();
    if (g == 0) {
        float m1 = mstat[qw][lq], l1 = lstat[qw][lq];
        float mm = fmaxf(m_r, m1);
        float a0 = __expf(m_r - mm), a1 = __expf(m1 - mm);
        float inv = 1.0f / (a0 * l_tot + a1 * l1);
        u16* bounce = (u16*)&V_lds[0][0][0] + (qw * 2 + dw) * (32 * 136);
        #pragma unroll
        for (int dt = 0; dt < 4; dt++)
            #pragma unroll
            for (int r = 0; r < 16; r++) {
                int drow = dt * 32 + (r & 3) + 8 * (r >> 2) + 4 * hi;
                float val = (a0 * o_acc[dt][r] + a1 * rb[drow * 32 + lq]) * inv;
                bounce[lq * 136 + drow] = f2bf(val);
            }
        asm volatile("s_waitcnt lgkmcnt(0)" ::: "memory");
        #pragma unroll
        for (int it = 0; it < 4; it++) {
            int qloc = it * 8 + (lane >> 3);
            int dch = (lane & 7) * 16;
            bf8_t lo8 = *(const bf8_t*)&bounce[qloc * 136 + dch];
            bf8_t hi8 = *(const bf8_t*)&bounce[qloc * 136 + dch + 8];
            u16* dst = O + (size_t)(b * 1024 + qb * 64 + qw * 32 + qloc) * 256 + dw * 128 + dch;
            *(bf8_t*)dst = lo8;
            *(bf8_t*)(dst + 8) = hi8;
        }
    }
#undef STAGE
}

extern "C" void kernel_launch(void* const* d_in, const int* in_sizes, int n_in,
                              void* d_out, int out_size, void* d_ws, size_t ws_size,
                              hipStream_t stream) {
    (void)in_sizes; (void)n_in; (void)out_size; (void)ws_size;
    const float* x   = (const float*)d_in[0];
    const float* lnw = (const float*)d_in[1];
    const float* lnb = (const float*)d_in[2];
    const float* wq  = (const float*)d_in[3];
    const float* bq  = (const float*)d_in[4];
    const float* wk  = (const float*)d_in[5];
    const float* bk  = (const float*)d_in[6];
    const float* wv  = (const float*)d_in[7];
    const float* bv  = (const float*)d_in[8];
    const float* wp  = (const float*)d_in[9];
    const float* bp  = (const float*)d_in[10];
    float* out = (float*)d_out;

    char* ws = (char*)d_ws;
    u16*   wcat  = (u16*)(ws);              // 768*256 bf16
    u16*   wpb   = (u16*)(ws + 0x60000);    // 256*256 bf16
    float* biasc = (float*)(ws + 0x80000);  // 768 f32
    u16*   hn    = (u16*)(ws + 0x90000);    // 16384*256 bf16   (8MB)
    u16*   qbuf  = (u16*)(ws + 0x890000);   // 16384*256 bf16   (8MB)
    u16*   kt    = (u16*)(ws + 0x1090000);  // [16][32][1024][8] bf16 (8MB)
    u16*   vt3   = (u16*)(ws + 0x1890000);  // [16][128][256][8] bf16 (8MB)
    u16*   O     = (u16*)(ws + 0x2090000);  // 16384*256 bf16   (8MB)

    prep_kernel<<<1028, 256, 0, stream>>>(wq, wk, wv, wp, bq, bk, bv, wcat, wpb, biasc);
    ln_kernel<<<256, 512, 0, stream>>>(x, lnw, lnb, hn);
    // QKV: [16384,768] = hn x wcat^T; epilogue routes Q/K/V into qbuf/kt/vt3
    gemm_bt<0><<<dim3(128, 6, 1), 256, 0, stream>>>(hn, wcat, qbuf, 256, 256, 768, 8,
                                                    0, 0, 0, biasc, nullptr, kt, vt3);
    // fused attention (swapped-operand, conflict-free LDS layouts)
    flash_kernel<<<256, 512, 0, stream>>>(qbuf, kt, vt3, O);
    // out[b] = wp x O[b]^T + bp + x  (f32)
    gemm_bt<3><<<dim3(2, 8, 16), 256, 0, stream>>>(wpb, O, out, 256, 256, 1024, 8,
                                                   0, 262144, 262144, bp, x,
                                                   nullptr, nullptr);
}